// Round 2
// baseline (210.210 us; speedup 1.0000x reference)
//
#include <hip/hip_runtime.h>
#include <hip/hip_bf16.h>
#include <math.h>

#define N_INIT 20000
#define LVLS   32
#define PP     1024
#define DD     64
#define DEE    128
#define N_TOT  (N_INIT + LVLS * PP)   // 52768

// workspace layout (floats): [0, N_TOT*DD) = store
// at byte offset ACC_OFF: int acc_i[4] = {n_good, n_sel, cnt_pos, cnt_negok}
// at ACC_OFF+16: float acc_f[1] = {loss}
#define STORE_FLOATS (N_TOT * DD)
#define ACC_OFF ((size_t)STORE_FLOATS * 4)

__device__ __forceinline__ float softplusf(float x) {
    return fmaxf(x, 0.f) + log1pf(expf(-fabsf(x)));
}

__global__ __launch_bounds__(256) void init_kernel(
    float* __restrict__ store, const int* __restrict__ thax,
    const float* __restrict__ init_table,
    const int* __restrict__ sel_mask, const int* __restrict__ good_mask,
    int* __restrict__ acc_i)
{
    int idx = blockIdx.x * 256 + threadIdx.x;
    if (idx < N_INIT * DD) {
        int i = idx >> 6, d = idx & 63;
        store[idx] = init_table[thax[i] * DD + d];
    }
    bool v  = idx < N_TOT;
    int  sm = v ? sel_mask[idx]  : 0;
    int  gm = v ? good_mask[idx] : 0;
    bool sel  = sm > 0;
    bool good = (gm > 0) && sel;
    unsigned long long ms = __ballot(sel);
    unsigned long long mg = __ballot(good);
    if ((threadIdx.x & 63) == 0) {
        if (mg) atomicAdd(&acc_i[0], __popcll(mg));
        if (ms) atomicAdd(&acc_i[1], __popcll(ms));
    }
}

// one node per block; 4 waves split the 128 input rows (32 each);
// within a wave: lane = r*16 + q; lane handles output cols 4q..4q+3, row slice r.
__global__ __launch_bounds__(256) void level_kernel(
    float* __restrict__ store,
    const int* __restrict__ parents, const int* __restrict__ rules,
    const float* __restrict__ W_rule, const float* __restrict__ b_rule,
    int l)
{
    int p   = blockIdx.x;
    int tid = threadIdx.x;
    int wid  = tid >> 6;
    int lane = tid & 63;
    int q = lane & 15;        // output col quad: cols 4q..4q+3
    int r = lane >> 4;        // row-within-group-of-4

    int base = N_INIT + l * PP;
    int pa = parents[(l * PP + p) * 2 + 0];
    int pb = parents[(l * PP + p) * 2 + 1];
    int ru = rules[l * PP + p];

    __shared__ float pe[2 * DD];
    __shared__ float partial[4][DD];

    if (tid < DD)            pe[tid]      = store[(size_t)pa * DD + tid];
    else if (tid < 2 * DD)   pe[tid]      = store[(size_t)pb * DD + (tid - DD)];
    __syncthreads();

    const float4* __restrict__ W4 = (const float4*)(W_rule + (size_t)ru * (2 * DD * DD));
    float4 acc = make_float4(0.f, 0.f, 0.f, 0.f);
#pragma unroll
    for (int i = 0; i < 8; ++i) {
        int row = wid * 32 + i * 4 + r;
        float4 w = W4[row * 16 + q];
        float  s = pe[row];
        acc.x = fmaf(s, w.x, acc.x);
        acc.y = fmaf(s, w.y, acc.y);
        acc.z = fmaf(s, w.z, acc.z);
        acc.w = fmaf(s, w.w, acc.w);
    }
    // reduce over r (lanes xor 16, 32)
#pragma unroll
    for (int off = 16; off <= 32; off <<= 1) {
        acc.x += __shfl_xor(acc.x, off, 64);
        acc.y += __shfl_xor(acc.y, off, 64);
        acc.z += __shfl_xor(acc.z, off, 64);
        acc.w += __shfl_xor(acc.w, off, 64);
    }
    if (r == 0) *(float4*)&partial[wid][4 * q] = acc;
    __syncthreads();

    if (tid < DD) {
        float h = partial[0][tid] + partial[1][tid] + partial[2][tid] + partial[3][tid]
                + b_rule[ru * DD + tid];
        store[((size_t)(base + p)) * DD + tid] = fmaxf(h, 0.f);
    }
}

// 32 nodes per block, 256 threads.
// thread t: g = t&31 -> output cols 4g..4g+3 ; n0 = t>>5 ; nodes {n0, n0+8, n0+16, n0+24}
__global__ __launch_bounds__(256) void eval_kernel(
    const float* __restrict__ store,
    const float* __restrict__ W1, const float* __restrict__ b1,
    const float* __restrict__ w2, const float* __restrict__ b2,
    const int* __restrict__ sel_mask, const int* __restrict__ good_mask,
    int* __restrict__ acc_i, float* __restrict__ acc_f)
{
    __shared__ float sW1[DD * DEE];     // [d][j], 32 KB
    __shared__ float sS[32][DD];        // 8 KB
    __shared__ float logitL[32];

    int t = threadIdx.x;
    int block_base = blockIdx.x * 32;

    for (int it = t; it < (DD * DEE) / 4; it += 256)
        ((float4*)sW1)[it] = ((const float4*)W1)[it];
    for (int it = t; it < 32 * (DD / 4); it += 256) {
        int node = it >> 4, qq = it & 15;
        ((float4*)sS[node])[qq] = ((const float4*)store)[(size_t)(block_base + node) * 16 + qq];
    }
    __syncthreads();

    int g  = t & 31;
    int n0 = t >> 5;
    const float4* W1v = (const float4*)sW1;
    float4 b1v = ((const float4*)b1)[g];
    float4 w2v = ((const float4*)w2)[g];

    float4 a0 = b1v, a1 = b1v, a2 = b1v, a3 = b1v;
#pragma unroll 4
    for (int d4 = 0; d4 < 16; ++d4) {
        float4 s0 = ((const float4*)sS[n0])[d4];
        float4 s1 = ((const float4*)sS[n0 +  8])[d4];
        float4 s2 = ((const float4*)sS[n0 + 16])[d4];
        float4 s3 = ((const float4*)sS[n0 + 24])[d4];
        const float* sp0 = (const float*)&s0;
        const float* sp1 = (const float*)&s1;
        const float* sp2 = (const float*)&s2;
        const float* sp3 = (const float*)&s3;
#pragma unroll
        for (int dd = 0; dd < 4; ++dd) {
            float4 w = W1v[(d4 * 4 + dd) * 32 + g];
            a0.x = fmaf(sp0[dd], w.x, a0.x); a0.y = fmaf(sp0[dd], w.y, a0.y);
            a0.z = fmaf(sp0[dd], w.z, a0.z); a0.w = fmaf(sp0[dd], w.w, a0.w);
            a1.x = fmaf(sp1[dd], w.x, a1.x); a1.y = fmaf(sp1[dd], w.y, a1.y);
            a1.z = fmaf(sp1[dd], w.z, a1.z); a1.w = fmaf(sp1[dd], w.w, a1.w);
            a2.x = fmaf(sp2[dd], w.x, a2.x); a2.y = fmaf(sp2[dd], w.y, a2.y);
            a2.z = fmaf(sp2[dd], w.z, a2.z); a2.w = fmaf(sp2[dd], w.w, a2.w);
            a3.x = fmaf(sp3[dd], w.x, a3.x); a3.y = fmaf(sp3[dd], w.y, a3.y);
            a3.z = fmaf(sp3[dd], w.z, a3.z); a3.w = fmaf(sp3[dd], w.w, a3.w);
        }
    }

    float p0 = fmaxf(a0.x, 0.f) * w2v.x + fmaxf(a0.y, 0.f) * w2v.y +
               fmaxf(a0.z, 0.f) * w2v.z + fmaxf(a0.w, 0.f) * w2v.w;
    float p1 = fmaxf(a1.x, 0.f) * w2v.x + fmaxf(a1.y, 0.f) * w2v.y +
               fmaxf(a1.z, 0.f) * w2v.z + fmaxf(a1.w, 0.f) * w2v.w;
    float p2 = fmaxf(a2.x, 0.f) * w2v.x + fmaxf(a2.y, 0.f) * w2v.y +
               fmaxf(a2.z, 0.f) * w2v.z + fmaxf(a2.w, 0.f) * w2v.w;
    float p3 = fmaxf(a3.x, 0.f) * w2v.x + fmaxf(a3.y, 0.f) * w2v.y +
               fmaxf(a3.z, 0.f) * w2v.z + fmaxf(a3.w, 0.f) * w2v.w;
#pragma unroll
    for (int off = 1; off < 32; off <<= 1) {
        p0 += __shfl_xor(p0, off, 32);
        p1 += __shfl_xor(p1, off, 32);
        p2 += __shfl_xor(p2, off, 32);
        p3 += __shfl_xor(p3, off, 32);
    }
    float b2v = b2[0];
    if (g == 0) {
        logitL[n0]      = p0 + b2v;
        logitL[n0 +  8] = p1 + b2v;
        logitL[n0 + 16] = p2 + b2v;
        logitL[n0 + 24] = p3 + b2v;
    }
    __syncthreads();

    if (t < 64) {
        bool valid = t < 32;
        int node = block_base + (t & 31);
        float logit = valid ? logitL[t & 31] : 0.f;
        int sm = valid ? sel_mask[node]  : 0;
        int gm = valid ? good_mask[node] : 0;
        bool sel  = sm > 0;
        bool good = (gm > 0) && sel;

        int ng = acc_i[0];
        int ns = acc_i[1];
        int nn = ns - ng;
        float pos_w = ng > 0 ? 0.85f / (float)ng : 1.0f;
        float neg_w = nn > 0 ? 0.15f / (float)nn : 1.0f;

        float bce = softplusf(logit) - logit * (good ? 1.f : 0.f);
        float w   = (good ? pos_w : neg_w) * (sel ? 1.f : 0.f);
        float contrib = valid ? w * bce : 0.f;

        bool pos_hit = valid && good && (logit >= 0.f);
        bool neg_hit = valid && sel && !good && (logit < 0.f);

        float c = contrib;
#pragma unroll
        for (int off = 32; off; off >>= 1) c += __shfl_down(c, off, 64);
        unsigned long long mp = __ballot(pos_hit);
        unsigned long long mn = __ballot(neg_hit);
        if (t == 0) {
            atomicAdd(acc_f, c);
            if (mp) atomicAdd(&acc_i[2], __popcll(mp));
            if (mn) atomicAdd(&acc_i[3], __popcll(mn));
        }
    }
}

__global__ void finalize_kernel(float* __restrict__ out,
                                const int* __restrict__ acc_i,
                                const float* __restrict__ acc_f)
{
    int ng = acc_i[0], ns = acc_i[1];
    int nn = ns - ng;
    out[0] = acc_f[0];
    out[1] = ng > 0 ? (float)acc_i[2] / (float)ng : 1.0f;
    out[2] = nn > 0 ? (float)acc_i[3] / (float)nn : 1.0f;
}

extern "C" void kernel_launch(void* const* d_in, const int* in_sizes, int n_in,
                              void* d_out, int out_size, void* d_ws, size_t ws_size,
                              hipStream_t stream) {
    const int*   thax       = (const int*)d_in[0];
    const int*   parents    = (const int*)d_in[1];
    const int*   rules      = (const int*)d_in[2];
    const int*   sel_mask   = (const int*)d_in[3];
    const int*   good_mask  = (const int*)d_in[4];
    const float* init_table = (const float*)d_in[5];
    const float* W_rule     = (const float*)d_in[6];
    const float* b_rule     = (const float*)d_in[7];
    const float* W1         = (const float*)d_in[8];
    const float* b1         = (const float*)d_in[9];
    const float* w2         = (const float*)d_in[10];
    const float* b2         = (const float*)d_in[11];

    float* store = (float*)d_ws;
    int*   acc_i = (int*)((char*)d_ws + ACC_OFF);
    float* acc_f = (float*)((char*)d_ws + ACC_OFF + 16);

    hipMemsetAsync((char*)d_ws + ACC_OFF, 0, 32, stream);

    init_kernel<<<(N_INIT * DD + 255) / 256, 256, 0, stream>>>(
        store, thax, init_table, sel_mask, good_mask, acc_i);

    for (int l = 0; l < LVLS; ++l)
        level_kernel<<<PP, 256, 0, stream>>>(store, parents, rules, W_rule, b_rule, l);

    eval_kernel<<<N_TOT / 32, 256, 0, stream>>>(
        store, W1, b1, w2, b2, sel_mask, good_mask, acc_i, acc_f);

    finalize_kernel<<<1, 1, 0, stream>>>((float*)d_out, acc_i, acc_f);
}